// Round 3
// baseline (224.778 us; speedup 1.0000x reference)
//
#include <hip/hip_runtime.h>

// Element-wise threshold-round with reversed output order.
// y[i] = (x[i]-trunc(x[i]) > thr) ? rint(x[i]) : floor(x[i]);  out = y[::-1]
//
// ROUND-3 PROBE: split-array within-bench A/B to pin the last ambiguity.
// Three structurally different kernels all measure 218-220 us; aggregate
// iteration roofline (2x512MiB harness fills + 256MiB kernel traffic at
// ~6.7 TB/s) is ~196-205 us. The only untested shared features of every
// prior "best" kernel are (1) the cross-lane reversal shuffle and (2) the
// nontemporal hints. This kernel runs BOTH variants, each on half the
// array, in one launch:
//   blocks [0, grid/2)    -> variant A: component-swap + shuffle l<->63-l,
//                            lane-ASCENDING nontemporal stores (proven path)
//   blocks [grid/2, grid) -> variant B: component-swap only, store directly
//                            to mirrored group (lane-DESCENDING contiguous
//                            within the same 1KiB segment), plain loads and
//                            stores (no nt, no shuffle, no LDS-pipe use)
// Readout: total ~219.5 -> no slack, declare roofline. ~212-215 -> B wins,
// go full-B. >221 -> descending stores break the coalescer, keep A.

typedef float vfloat4 __attribute__((ext_vector_type(4)));

constexpr int BLOCK = 256;
constexpr int GPT = 4;             // groups per thread
constexpr int GPB = BLOCK * GPT;   // 1024 groups per block (16 KiB in/out)

__device__ __forceinline__ float thr_round(float x, float thr) {
    float f = x - truncf(x);
    return (f > thr) ? rintf(x) : floorf(x);
}

// op with component reversal: r = {op(v.w), op(v.z), op(v.y), op(v.x)}
__device__ __forceinline__ vfloat4 comp_rev_op(vfloat4 v, float thr) {
    vfloat4 r;
    r.x = thr_round(v.w, thr);
    r.y = thr_round(v.z, thr);
    r.z = thr_round(v.y, thr);
    r.w = thr_round(v.x, thr);
    return r;
}

__device__ __forceinline__ vfloat4 lane_rev(vfloat4 r, int src) {
    vfloat4 s;
    s.x = __shfl(r.x, src);
    s.y = __shfl(r.y, src);
    s.z = __shfl(r.z, src);
    s.w = __shfl(r.w, src);
    return s;
}

__global__ __launch_bounds__(BLOCK) void threshold_rev_kernel(
    const vfloat4* __restrict__ x4,
    const float* __restrict__ threshold,
    vfloat4* __restrict__ out4,
    int n4 /* number of float4 groups = N/4; multiple of 64 */) {
    const float thr = threshold[0];
    const int tid = threadIdx.x;
    const int lane = tid & 63;
    const int gb = blockIdx.x * GPB;    // first group owned by this block
    const unsigned half = gridDim.x >> 1;

    if (blockIdx.x < half) {
        // ---- Variant A: shuffle + nontemporal (the proven structure) ----
        const int src = 63 - lane;
        if (gb + GPB <= n4) {
            const int t0 = gb + tid;
            const int t1 = t0 + BLOCK;
            const int t2 = t0 + 2 * BLOCK;
            const int t3 = t0 + 3 * BLOCK;
            vfloat4 v0 = __builtin_nontemporal_load(&x4[t0]);
            vfloat4 v1 = __builtin_nontemporal_load(&x4[t1]);
            vfloat4 v2 = __builtin_nontemporal_load(&x4[t2]);
            vfloat4 v3 = __builtin_nontemporal_load(&x4[t3]);
            vfloat4 s0 = lane_rev(comp_rev_op(v0, thr), src);
            vfloat4 s1 = lane_rev(comp_rev_op(v1, thr), src);
            vfloat4 s2 = lane_rev(comp_rev_op(v2, thr), src);
            vfloat4 s3 = lane_rev(comp_rev_op(v3, thr), src);
            // input group of lane (63-l) is wave_base+63-l; output group is
            // n4-1-(wave_base+63-l) = (n4-64-wave_base)+l -> lane-ascending.
            __builtin_nontemporal_store(s0, &out4[(n4 - 64 - (t0 - lane)) + lane]);
            __builtin_nontemporal_store(s1, &out4[(n4 - 64 - (t1 - lane)) + lane]);
            __builtin_nontemporal_store(s2, &out4[(n4 - 64 - (t2 - lane)) + lane]);
            __builtin_nontemporal_store(s3, &out4[(n4 - 64 - (t3 - lane)) + lane]);
        } else {
            for (int k = 0; k < GPT; ++k) {
                const int t = gb + tid + k * BLOCK;
                if (t < n4) {
                    vfloat4 v = __builtin_nontemporal_load(&x4[t]);
                    vfloat4 s = lane_rev(comp_rev_op(v, thr), src);
                    __builtin_nontemporal_store(s, &out4[(n4 - 64 - (t - lane)) + lane]);
                }
            }
        }
    } else {
        // ---- Variant B: no shuffle, plain loads/stores ----
        // Thread with input group t writes component-reversed result to
        // mirrored group n4-1-t. Within a wave the 64 stores cover ONE
        // contiguous 1 KiB segment (lane-descending order) -> coalescer
        // test: same cache-line set as variant A, different lane order.
        if (gb + GPB <= n4) {
            const int t0 = gb + tid;
            const int t1 = t0 + BLOCK;
            const int t2 = t0 + 2 * BLOCK;
            const int t3 = t0 + 3 * BLOCK;
            vfloat4 v0 = x4[t0];
            vfloat4 v1 = x4[t1];
            vfloat4 v2 = x4[t2];
            vfloat4 v3 = x4[t3];
            vfloat4 r0 = comp_rev_op(v0, thr);
            vfloat4 r1 = comp_rev_op(v1, thr);
            vfloat4 r2 = comp_rev_op(v2, thr);
            vfloat4 r3 = comp_rev_op(v3, thr);
            out4[n4 - 1 - t0] = r0;
            out4[n4 - 1 - t1] = r1;
            out4[n4 - 1 - t2] = r2;
            out4[n4 - 1 - t3] = r3;
        } else {
            for (int k = 0; k < GPT; ++k) {
                const int t = gb + tid + k * BLOCK;
                if (t < n4) {
                    out4[n4 - 1 - t] = comp_rev_op(x4[t], thr);
                }
            }
        }
    }
}

extern "C" void kernel_launch(void* const* d_in, const int* in_sizes, int n_in,
                              void* d_out, int out_size, void* d_ws, size_t ws_size,
                              hipStream_t stream) {
    const vfloat4* x4 = (const vfloat4*)d_in[0];
    const float* thr = (const float*)d_in[1];
    vfloat4* out4 = (vfloat4*)d_out;
    int n = in_sizes[0];       // 33554432
    int n4 = n / 4;            // 8388608 groups
    int grid = (n4 + GPB - 1) / GPB;   // 8192 blocks, dense mapping
    threshold_rev_kernel<<<grid, BLOCK, 0, stream>>>(x4, thr, out4, n4);
}